// Round 3
// baseline (109.630 us; speedup 1.0000x reference)
//
#include <hip/hip_runtime.h>

#define N_NODES 100000
#define N_EDGES 1000000
#define D 64
#define N_GRAPHS 512

// K1: y[v] = dot(x[v, :], W[0, :])   -- 16 threads per node, float4 each
__global__ __launch_bounds__(256) void dot_kernel(const float* __restrict__ x,
                                                  const float* __restrict__ W,
                                                  float* __restrict__ y) {
    int t = blockIdx.x * blockDim.x + threadIdx.x;
    int v = t >> 4;      // node index
    int sub = t & 15;    // 16 sub-lanes cover 64 floats via float4
    if (v >= N_NODES) return;
    const float4 xv = *reinterpret_cast<const float4*>(x + (size_t)v * D + sub * 4);
    const float4 wv = *reinterpret_cast<const float4*>(W + sub * 4);
    float p = xv.x * wv.x + xv.y * wv.y + xv.z * wv.z + xv.w * wv.w;
    // reduce across the 16-lane group (stays inside the 64-lane wave)
    p += __shfl_xor(p, 1, 64);
    p += __shfl_xor(p, 2, 64);
    p += __shfl_xor(p, 4, 64);
    p += __shfl_xor(p, 8, 64);
    if (sub == 0) y[v] = p;
}

// K2: acc[batch[dst_e]] += edge_attr[e] * y[src_e], via per-block LDS histogram
__global__ __launch_bounds__(256) void edge_kernel(const int* __restrict__ ei,
                                                   const float* __restrict__ ea,
                                                   const int* __restrict__ batch,
                                                   const float* __restrict__ y,
                                                   float* __restrict__ acc) {
    __shared__ float sacc[N_GRAPHS];
    for (int i = threadIdx.x; i < N_GRAPHS; i += blockDim.x) sacc[i] = 0.0f;
    __syncthreads();
    const int* __restrict__ srcp = ei;            // edge_index[0, :]
    const int* __restrict__ dstp = ei + N_EDGES;  // edge_index[1, :]
    const int stride = gridDim.x * blockDim.x;
    for (int e = blockIdx.x * blockDim.x + threadIdx.x; e < N_EDGES; e += stride) {
        int s = srcp[e];
        int d = dstp[e];
        int g = batch[d];
        atomicAdd(&sacc[g], ea[e] * y[s]);
    }
    __syncthreads();
    // one flush per bin: i takes tid and tid+256, each bin exactly once
    for (int i = threadIdx.x; i < N_GRAPHS; i += blockDim.x) {
        float v = sacc[i];
        if (v != 0.0f) atomicAdd(&acc[i], v);
    }
}

// K3: counts via binary search on sorted batch; out[g] = acc[g]/max(cnt,1) + b
__global__ __launch_bounds__(512) void final_kernel(const int* __restrict__ batch,
                                                    const float* __restrict__ acc,
                                                    const float* __restrict__ bptr,
                                                    float* __restrict__ out) {
    int g = threadIdx.x;  // one block of 512 threads
    // lower_bound(batch, g) and lower_bound(batch, g+1)
    int lo0 = 0, hi0 = N_NODES;
    while (lo0 < hi0) { int mid = (lo0 + hi0) >> 1; if (batch[mid] < g) lo0 = mid + 1; else hi0 = mid; }
    int lo1 = 0, hi1 = N_NODES;
    while (lo1 < hi1) { int mid = (lo1 + hi1) >> 1; if (batch[mid] < g + 1) lo1 = mid + 1; else hi1 = mid; }
    float cnt = (float)(hi1 - lo0);
    out[g] = acc[g] / fmaxf(cnt, 1.0f) + bptr[0];
}

extern "C" void kernel_launch(void* const* d_in, const int* in_sizes, int n_in,
                              void* d_out, int out_size, void* d_ws, size_t ws_size,
                              hipStream_t stream) {
    const float* x     = (const float*)d_in[0];  // [N, 64] fp32
    const int*   ei    = (const int*)  d_in[1];  // [2, E] int32
    const float* ea    = (const float*)d_in[2];  // [E] fp32
    const int*   batch = (const int*)  d_in[3];  // [N] int32, sorted
    const float* W     = (const float*)d_in[4];  // [1, 64] fp32
    const float* b     = (const float*)d_in[5];  // [1] fp32
    float* out = (float*)d_out;                  // [G, 1] = 512 fp32

    float* y   = (float*)d_ws;                   // N_NODES floats
    float* acc = y + N_NODES;                    // N_GRAPHS floats

    hipMemsetAsync(acc, 0, N_GRAPHS * sizeof(float), stream);

    // N_NODES * 16 threads / 256 = 6250 blocks
    dot_kernel<<<(N_NODES * 16 + 255) / 256, 256, 0, stream>>>(x, W, y);
    edge_kernel<<<256, 256, 0, stream>>>(ei, ea, batch, y, acc);
    final_kernel<<<1, 512, 0, stream>>>(batch, acc, b, out);
}